// Round 7
// baseline (202.899 us; speedup 1.0000x reference)
//
#include <hip/hip_runtime.h>
#include <math.h>

// Problem constants
#define B_SZ 2
#define SEQ 512
#define DM 1024
#define DI 2048
#define DS 32
#define TOK (B_SZ*SEQ)        // 1024
#define NCH 16                // scan chunks
#define CLEN (SEQ/NCH)        // 32
#define NPAIRH 32768          // (b, d-pair, j) chain-pair ids

// fused weight layout (rows of K=1024, bf16):
//   [0,4096) W_in | [4096,6144) W_dt | [6144,6176) W_B | [6176,6208) W_C | [6208,6272) pad
#define NFUSED 6272

typedef float v2f __attribute__((ext_vector_type(2)));

__device__ __forceinline__ unsigned short f2bf(float f) {
  unsigned int u = __builtin_bit_cast(unsigned int, f);
  unsigned int r = u + 0x7fffu + ((u >> 16) & 1u);   // RNE (inputs finite)
  return (unsigned short)(r >> 16);
}

// ---- packed-FP32 (VOP3P) helpers: 1 instruction per 2-wide op ----
static __device__ __forceinline__ v2f pk_fma(v2f a, v2f b, v2f c) {
  v2f d;
  asm("v_pk_fma_f32 %0, %1, %2, %3" : "=v"(d) : "v"(a), "v"(b), "v"(c));
  return d;
}
static __device__ __forceinline__ v2f pk_fms(v2f a, v2f b, v2f c) {
  v2f d;
  asm("v_pk_fma_f32 %0, %1, %2, %3 neg_lo:[0,0,1] neg_hi:[0,0,1]"
      : "=v"(d) : "v"(a), "v"(b), "v"(c));
  return d;
}
static __device__ __forceinline__ v2f pk_mul(v2f a, v2f b) {
  v2f d;
  asm("v_pk_mul_f32 %0, %1, %2" : "=v"(d) : "v"(a), "v"(b));
  return d;
}
static __device__ __forceinline__ v2f pk_add(v2f a, v2f b) {
  v2f d;
  asm("v_pk_add_f32 %0, %1, %2" : "=v"(d) : "v"(a), "v"(b));
  return d;
}
// d = a * bcast(b.LO) + c   (src1 hi half reads its LO 32 bits)
static __device__ __forceinline__ v2f pk_fma_b(v2f a, v2f b, v2f c) {
  v2f d;
  asm("v_pk_fma_f32 %0, %1, %2, %3 op_sel_hi:[1,0,1]"
      : "=v"(d) : "v"(a), "v"(b), "v"(c));
  return d;
}
// d = a * bcast(b.LO)
static __device__ __forceinline__ v2f pk_mul_b(v2f a, v2f b) {
  v2f d;
  asm("v_pk_mul_f32 %0, %1, %2 op_sel_hi:[1,0]"
      : "=v"(d) : "v"(a), "v"(b));
  return d;
}

// DPP row-rotate add: sums over the 16-lane row with 4 VALU ops (no LDS pipe).
template<int CTRL>
__device__ __forceinline__ float row_ror_add(float x) {
  int s = __builtin_amdgcn_update_dpp(0, __builtin_bit_cast(int, x), CTRL, 0xf, 0xf, false);
  return x + __builtin_bit_cast(float, s);
}
__device__ __forceinline__ float row16_sum(float v) {
  v = row_ror_add<0x121>(v);
  v = row_ror_add<0x122>(v);
  v = row_ror_add<0x124>(v);
  v = row_ror_add<0x128>(v);
  return v;
}

// ---------------- fused fp32 -> bf16 cast of all 6 tensors, 8 elems/thread ----------------
__global__ __launch_bounds__(256) void fused_cast(const float* __restrict__ x,
                                                  const float* __restrict__ W_in,
                                                  const float* __restrict__ W_dt,
                                                  const float* __restrict__ W_B,
                                                  const float* __restrict__ W_C,
                                                  const float* __restrict__ W_out,
                                                  unsigned short* __restrict__ xb,
                                                  unsigned short* __restrict__ wcat,
                                                  unsigned short* __restrict__ wob) {
  int g = blockIdx.x * 256 + threadIdx.x;
  const float* s; unsigned short* dd; int off;
  if      (g <  131072) { s = x;     dd = xb;             off = 0; }
  else if (g <  655360) { s = W_in;  dd = wcat;           off = 131072; }
  else if (g <  917504) { s = W_dt;  dd = wcat + 4194304; off = 655360; }
  else if (g <  921600) { s = W_B;   dd = wcat + 6291456; off = 917504; }
  else if (g <  925696) { s = W_C;   dd = wcat + 6324224; off = 921600; }
  else if (g < 1187840) { s = W_out; dd = wob;            off = 925696; }
  else return;
  int i = g - off;
  float4 a = ((const float4*)s)[i * 2];
  float4 b = ((const float4*)s)[i * 2 + 1];
  union { unsigned short us[8]; uint4 v; } o;
  o.us[0] = f2bf(a.x); o.us[1] = f2bf(a.y); o.us[2] = f2bf(a.z); o.us[3] = f2bf(a.w);
  o.us[4] = f2bf(b.x); o.us[5] = f2bf(b.y); o.us[6] = f2bf(b.z); o.us[7] = f2bf(b.w);
  ((uint4*)dd)[i] = o.v;
}

// ---------------- bf16 MFMA GEMM machinery ----------
typedef __attribute__((ext_vector_type(8))) short  frag8;
typedef __attribute__((ext_vector_type(4))) float  facc4;

__device__ __forceinline__ void gload_lds16(const unsigned short* g, unsigned short* l) {
  __builtin_amdgcn_global_load_lds((const __attribute__((address_space(1))) unsigned int*)g,
                                   (__attribute__((address_space(3))) unsigned int*)l, 16, 0, 0);
}
__device__ __forceinline__ void gload_lds16f(const float* g, float* l) {
  __builtin_amdgcn_global_load_lds((const __attribute__((address_space(1))) unsigned int*)g,
                                   (__attribute__((address_space(3))) unsigned int*)l, 16, 0, 0);
}

__device__ __forceinline__ float softplus_fast(float v) {
  return fmaxf(v, 0.f) + __logf(1.f + __expf(-fabsf(v)));
}

// ---------------- GEMM1: 128(M)x64(N) tile, BK=64, XOR-swizzled LDS, routed epilogue ------
__global__ __launch_bounds__(256) void gemm1_big(const unsigned short* __restrict__ A,
                                                 const unsigned short* __restrict__ Bw,
                                                 float* __restrict__ o_xs,
                                                 float* __restrict__ o_zb,
                                                 float* __restrict__ o_dts,
                                                 float* __restrict__ o_bcb,
                                                 const float* __restrict__ b_dt,
                                                 const float* __restrict__ dt_bias) {
  __shared__ __align__(16) unsigned short As[128 * 64];   // 16 KB
  __shared__ __align__(16) unsigned short Bs[64 * 64];    // 8 KB
  const int K = DM;
  const int tid = threadIdx.x;
  const int w = tid >> 6, lane = tid & 63;
  const int wm = w >> 1, wn = w & 1;
  const int bid = blockIdx.x;
  const int Wk = (bid & 7) * 98 + (bid >> 3);   // XCD-contiguous walk
  const int m0 = (Wk & 7) * 128;                // 8 m-tiles share one B n-column per XCD chunk
  const int n0 = (Wk >> 3) * 64;
  const int r = lane & 15, q = lane >> 4;
  const int srow = lane >> 3;                   // staging row-in-chunk (0..7)
  const int scol = ((lane & 7) ^ srow) * 8;     // XOR-swizzled source k-seg
  facc4 acc[4][2] = {};
  const unsigned short* Ag = A + (size_t)m0 * K;
  const unsigned short* Bg = Bw + (size_t)n0 * K;

  for (int k0 = 0; k0 < DM; k0 += 64) {
#pragma unroll
    for (int k = 0; k < 4; ++k) {               // A: 16 chunks of 8 rows x 64 k (1 KB)
      int ch = w * 4 + k;
      gload_lds16(Ag + (size_t)(ch * 8 + srow) * K + k0 + scol, &As[ch * 512]);
    }
#pragma unroll
    for (int k = 0; k < 2; ++k) {               // B: 8 chunks
      int ch = w * 2 + k;
      gload_lds16(Bg + (size_t)(ch * 8 + srow) * K + k0 + scol, &Bs[ch * 512]);
    }
    __syncthreads();                            // drains global_load_lds
#pragma unroll
    for (int kk = 0; kk < 2; ++kk) {
      frag8 af[4], bfr[2];
      const int sw = ((kk * 4 + q) ^ (r & 7)) * 8;    // swizzled seg offset (row&7 == r&7)
#pragma unroll
      for (int i = 0; i < 4; ++i)
        af[i] = *(const frag8*)&As[(wm * 64 + i * 16 + r) * 64 + sw];
#pragma unroll
      for (int jj = 0; jj < 2; ++jj)
        bfr[jj] = *(const frag8*)&Bs[(wn * 32 + jj * 16 + r) * 64 + sw];
#pragma unroll
      for (int i = 0; i < 4; ++i)
#pragma unroll
        for (int jj = 0; jj < 2; ++jj)
          acc[i][jj] = __builtin_amdgcn_mfma_f32_16x16x32_bf16(af[i], bfr[jj], acc[i][jj], 0, 0, 0);
    }
    __syncthreads();
  }

#pragma unroll
  for (int i = 0; i < 4; ++i) {
#pragma unroll
    for (int jj = 0; jj < 2; ++jj) {
      int n = n0 + wn * 32 + jj * 16 + r;
      int mb = m0 + wm * 64 + i * 16 + q * 4;
      if (n < 2048) {
#pragma unroll
        for (int rg = 0; rg < 4; ++rg)
          o_xs[(size_t)(mb + rg) * DI + n] = acc[i][jj][rg];
      } else if (n < 4096) {
#pragma unroll
        for (int rg = 0; rg < 4; ++rg)
          o_zb[(size_t)(mb + rg) * DI + (n - 2048)] = acc[i][jj][rg];
      } else if (n < 6144) {
        int d = n - 4096;
        float bias = b_dt[d] + dt_bias[d];
#pragma unroll
        for (int rg = 0; rg < 4; ++rg)
          o_dts[(size_t)(mb + rg) * DI + d] = softplus_fast(acc[i][jj][rg] + bias);
      } else if (n < 6176) {
#pragma unroll
        for (int rg = 0; rg < 4; ++rg)
          o_bcb[(size_t)(mb + rg) * DS + (n - 6144)] = acc[i][jj][rg];
      } else if (n < 6208) {
#pragma unroll
        for (int rg = 0; rg < 4; ++rg)
          o_bcb[(size_t)TOK * DS + (size_t)(mb + rg) * DS + (n - 6176)] = acc[i][jj][rg];
      }
    }
  }
}

// ---------------- GEMM2: out = ln @ W_out^T with IN-BLOCK split-K (8 waves) ----------------
__global__ __launch_bounds__(512) void gemm2_fused(const unsigned short* __restrict__ A,
                                                   const unsigned short* __restrict__ Bw,
                                                   float* __restrict__ o_c) {
  __shared__ __align__(16) unsigned short As[2][64 * 64];   // 16 KB
  __shared__ __align__(16) unsigned short Bs[2][64 * 64];   // 16 KB
  const int K = DI;
  const int tid = threadIdx.x;
  const int grp = tid >> 8;                     // 0 or 1 (split-K half)
  const int w = (tid >> 6) & 3;
  const int lane = tid & 63;
  const int wm = w >> 1, wn = w & 1;
  const int bid = blockIdx.x;
  const int Wk = (bid & 7) * 32 + (bid >> 3);   // 256 blocks, bijective XCD walk
  const int m0 = (Wk % 16) * 64;
  const int n0 = (Wk / 16) * 64;
  const int r = lane & 15, q = lane >> 4;
  const int srow = lane >> 3;
  const int scol = ((lane & 7) ^ srow) * 8;
  facc4 acc[2][2] = {};
  const unsigned short* Ag = A + (size_t)m0 * K + grp * 1024;
  const unsigned short* Bg = Bw + (size_t)n0 * K + grp * 1024;
  unsigned short* Asg = As[grp];
  unsigned short* Bsg = Bs[grp];

  for (int k0 = 0; k0 < 1024; k0 += 64) {
#pragma unroll
    for (int k = 0; k < 2; ++k) {
      int ch = w * 2 + k;                // 8 chunks of 8 rows x 64 k per group
      gload_lds16(Ag + (size_t)(ch * 8 + srow) * K + k0 + scol, &Asg[ch * 512]);
      gload_lds16(Bg + (size_t)(ch * 8 + srow) * K + k0 + scol, &Bsg[ch * 512]);
    }
    __syncthreads();
#pragma unroll
    for (int kk = 0; kk < 2; ++kk) {
      frag8 af[2], bf[2];
      const int sw = ((kk * 4 + q) ^ (r & 7)) * 8;
#pragma unroll
      for (int i = 0; i < 2; ++i)
        af[i] = *(const frag8*)&Asg[(wm * 32 + i * 16 + r) * 64 + sw];
#pragma unroll
      for (int jj = 0; jj < 2; ++jj)
        bf[jj] = *(const frag8*)&Bsg[(wn * 32 + jj * 16 + r) * 64 + sw];
#pragma unroll
      for (int i = 0; i < 2; ++i)
#pragma unroll
        for (int jj = 0; jj < 2; ++jj)
          acc[i][jj] = __builtin_amdgcn_mfma_f32_16x16x32_bf16(af[i], bf[jj], acc[i][jj], 0, 0, 0);
    }
    __syncthreads();
  }

  // cross-group reduce via LDS (reuse As[0]: 16 KB holds the 64x64 fp32 tile)
  float* red = (float*)&As[0][0];
  if (grp == 1) {
#pragma unroll
    for (int i = 0; i < 2; ++i)
#pragma unroll
      for (int jj = 0; jj < 2; ++jj) {
        int coln = wn * 32 + jj * 16 + r;
        int rowb = wm * 32 + i * 16 + q * 4;
#pragma unroll
        for (int rg = 0; rg < 4; ++rg)
          red[(rowb + rg) * 64 + coln] = acc[i][jj][rg];
      }
  }
  __syncthreads();
  if (grp == 0) {
#pragma unroll
    for (int i = 0; i < 2; ++i)
#pragma unroll
      for (int jj = 0; jj < 2; ++jj) {
        int coln = wn * 32 + jj * 16 + r;
        int rowb = wm * 32 + i * 16 + q * 4;
#pragma unroll
        for (int rg = 0; rg < 4; ++rg)
          o_c[(size_t)(m0 + rowb + rg) * DM + n0 + coln] =
              acc[i][jj][rg] + red[(rowb + rg) * 64 + coln];
      }
  }
}

// ---------------- chunked scan, packed-FP32, NCH=16, hierarchical compose ----------------
// Per (d,j): h = dt*A/2 (|h|<=0.07); inv = 1/(1-h) ~= 1+h+h^2+h^3;
// A_bar = 2*inv-1; s' = inv*(2s + dt*x*B) - s; then rotate (r,i).
__global__ __launch_bounds__(256) void scan_p1(const float* __restrict__ xs,
                                               const float* __restrict__ dts,
                                               const float* __restrict__ bcb,
                                               const float* __restrict__ A_log,
                                               const float* __restrict__ rope,
                                               float* __restrict__ Pbuf) {
  __shared__ __align__(16) float lds[3072];     // 12 KB: xs | dts | B
  const int blk = blockIdx.x;           // 1920 = 15 chunks x 128 (chunk 15's P,u never consumed)
  const int c = blk >> 7;
  const int sub = blk & 127;
  const int b = sub >> 6;
  const int dbase = (sub & 63) << 5;
  const int tid = threadIdx.x;
  const int wv = tid >> 6, lane = tid & 63;
  const int j = tid & 15;
  const int ca = (tid >> 4) & 15;
  const int l0 = c * CLEN;
  const size_t base = (size_t)(b * SEQ + l0);

  {
    int row = wv * 8 + (lane >> 3);     // 0..31 token within chunk
    int col = (lane & 7) << 2;
    gload_lds16f(xs  + (base + row) * DI + dbase + col, &lds[wv * 256]);
    gload_lds16f(dts + (base + row) * DI + dbase + col, &lds[1024 + wv * 256]);
    gload_lds16f(bcb + base * DS + wv * 256 + lane * 4, &lds[2048 + wv * 256]);
  }

  const int dA = dbase + 2 * ca;
  v2f Ar, Ai;
  Ar.x = -0.5f * __expf(A_log[dA * DS + j]);
  Ar.y = -0.5f * __expf(A_log[(dA + 1) * DS + j]);
  Ai.x = -0.5f * __expf(A_log[dA * DS + j + 16]);
  Ai.y = -0.5f * __expf(A_log[(dA + 1) * DS + j + 16]);
  const float fr = rope[j];
  float sn0, cs0, sFs, cFs;
  __sincosf((float)l0 * fr, &sn0, &cs0);
  __sincosf(fr, &sFs, &cFs);
  const v2f one = {1.f, 1.f};
  const v2f two = {2.f, 2.f};
  v2f cs2 = {cs0, cs0}, sn2 = {sn0, sn0};
  const v2f cF2 = {cFs, cFs}, sF2 = {sFs, sFs};
  __syncthreads();

  v2f p00 = one, p01 = {0.f, 0.f}, p10 = {0.f, 0.f}, p11 = one;
  v2f ur = {0.f, 0.f}, ui = {0.f, 0.f};

#pragma unroll 4
  for (int tt = 0; tt < CLEN; ++tt) {
    const int ro = tt * 32;
    v2f xin = *(const v2f*)&lds[ro + 2 * ca];
    v2f dtd = *(const v2f*)&lds[1024 + ro + 2 * ca];
    v2f Br2, Bi2;                         // lo-only; hi broadcast via op_sel_hi
    Br2.x = lds[2048 + ro + j];
    Bi2.x = lds[2048 + ro + j + 16];
    v2f hr = pk_mul(dtd, Ar), hi2 = pk_mul(dtd, Ai);
    v2f invr = pk_fma(hr, pk_fma(hr, pk_add(hr, one), one), one);
    v2f invi = pk_fma(hi2, pk_fma(hi2, pk_add(hi2, one), one), one);
    v2f dx = pk_mul(dtd, xin);
    v2f gr = pk_fma_b(dx, Br2, pk_add(ur, ur));
    v2f gi = pk_fma_b(dx, Bi2, pk_add(ui, ui));
    v2f tr = pk_fms(invr, gr, ur);
    v2f ti = pk_fms(invi, gi, ui);
    ur = pk_fms(tr, cs2, pk_mul(ti, sn2));
    ui = pk_fma(tr, sn2, pk_mul(ti, cs2));
    v2f Abr = pk_fms(invr, two, one);
    v2f Abi = pk_fms(invi, two, one);
    v2f q00 = pk_mul(Abr, p00), q01 = pk_mul(Abr, p01);
    v2f q10 = pk_mul(Abi, p10), q11 = pk_mul(Abi, p11);
    p00 = pk_fms(q00, cs2, pk_mul(q10, sn2));
    p10 = pk_fma(q00, sn2, pk_mul(q10, cs2));
    p01 = pk_fms(q01, cs2, pk_mul(q11, sn2));
    p11 = pk_fma(q01, sn2, pk_mul(q11, cs2));
    v2f ocs = cs2;
    cs2 = pk_fms(cs2, cF2, pk_mul(sn2, sF2));
    sn2 = pk_fma(sn2, cF2, pk_mul(ocs, sF2));
  }
  const int pc = (b * 1024 + (dbase >> 1) + ca) * 16 + j;
  float2* Pb2 = (float2*)Pbuf;
  Pb2[(c * 6 + 0) * NPAIRH + pc] = make_float2(p00.x, p00.y);
  Pb2[(c * 6 + 1) * NPAIRH + pc] = make_float2(p01.x, p01.y);
  Pb2[(c * 6 + 2) * NPAIRH + pc] = make_float2(p10.x, p10.y);
  Pb2[(c * 6 + 3) * NPAIRH + pc] = make_float2(p11.x, p11.y);
  Pb2[(c * 6 + 4) * NPAIRH + pc] = make_float2(ur.x, ur.y);
  Pb2[(c * 6 + 5) * NPAIRH + pc] = make_float2(ui.x, ui.y);
}

// ---- p2: sequential compose of the 15 chunk transfers -> per-chunk entry states ----
// One thread per chain-pair (32768). Reads 15x6 float2 (coalesced), writes 16 float4.
// Removes scan_p3's O(NCH^2) inline compose (189 MB L2/L3 + ~45 scattered loads/thread).
__global__ __launch_bounds__(256) void scan_p2(const float* __restrict__ Pbuf,
                                               float* __restrict__ Sbuf) {
  const int pc = blockIdx.x * 256 + threadIdx.x;
  const float2* Pb2 = (const float2*)Pbuf;
  float4* Sb = (float4*)Sbuf;
  v2f sr = {0.f, 0.f}, si = {0.f, 0.f};
  Sb[pc] = make_float4(0.f, 0.f, 0.f, 0.f);      // chunk 0 entry
  for (int k = 0; k < NCH - 1; ++k) {
    float2 f;
    f = Pb2[(k * 6 + 0) * NPAIRH + pc]; v2f p00 = {f.x, f.y};
    f = Pb2[(k * 6 + 1) * NPAIRH + pc]; v2f p01 = {f.x, f.y};
    f = Pb2[(k * 6 + 2) * NPAIRH + pc]; v2f p10 = {f.x, f.y};
    f = Pb2[(k * 6 + 3) * NPAIRH + pc]; v2f p11 = {f.x, f.y};
    f = Pb2[(k * 6 + 4) * NPAIRH + pc]; v2f ur  = {f.x, f.y};
    f = Pb2[(k * 6 + 5) * NPAIRH + pc]; v2f ui  = {f.x, f.y};
    v2f nr = p00 * sr + p01 * si + ur;
    v2f ni = p10 * sr + p11 * si + ui;
    sr = nr; si = ni;
    Sb[(size_t)(k + 1) * NPAIRH + pc] = make_float4(sr.x, sr.y, si.x, si.y);
  }
}

__global__ __launch_bounds__(256) void scan_p3(const float* __restrict__ xs,
                                               const float* __restrict__ dts,
                                               const float* __restrict__ bcb,
                                               const float* __restrict__ A_log,
                                               const float* __restrict__ rope,
                                               const float* __restrict__ Sbuf,
                                               float* __restrict__ y,
                                               float* __restrict__ fstate) {
  __shared__ __align__(16) float lds[4096];     // 16 KB: xs | dts | B | C
  const int blk = blockIdx.x;           // 2048
  const int c = blk >> 7;
  const int sub = blk & 127;
  const int b = sub >> 6;
  const int dbase = (sub & 63) << 5;
  const int tid = threadIdx.x;
  const int wv = tid >> 6, lane = tid & 63;
  const int j = tid & 15;
  const int ca = (tid >> 4) & 15;
  const int l0 = c * CLEN;
  const size_t base = (size_t)(b * SEQ + l0);

  {
    int row = wv * 8 + (lane >> 3);
    int col = (lane & 7) << 2;
    gload_lds16f(xs  + (base + row) * DI + dbase + col, &lds[wv * 256]);
    gload_lds16f(dts + (base + row) * DI + dbase + col, &lds[1024 + wv * 256]);
    gload_lds16f(bcb + base * DS + wv * 256 + lane * 4, &lds[2048 + wv * 256]);
    gload_lds16f(bcb + (size_t)TOK * DS + base * DS + wv * 256 + lane * 4,
                 &lds[3072 + wv * 256]);
  }

  // entry state: one coalesced float4 load (computed by scan_p2)
  const int pc = (b * 1024 + (dbase >> 1) + ca) * 16 + j;
  float4 f0 = ((const float4*)Sbuf)[(size_t)c * NPAIRH + pc];
  v2f sr = {f0.x, f0.y}, si = {f0.z, f0.w};

  const int dA = dbase + 2 * ca;
  v2f Ar, Ai;
  Ar.x = -0.5f * __expf(A_log[dA * DS + j]);
  Ar.y = -0.5f * __expf(A_log[(dA + 1) * DS + j]);
  Ai.x = -0.5f * __expf(A_log[dA * DS + j + 16]);
  Ai.y = -0.5f * __expf(A_log[(dA + 1) * DS + j + 16]);
  const float fr = rope[j];
  float sn0, cs0, sFs, cFs;
  __sincosf((float)l0 * fr, &sn0, &cs0);
  __sincosf(fr, &sFs, &cFs);
  const v2f one = {1.f, 1.f};
  v2f cs2 = {cs0, cs0}, sn2 = {sn0, sn0};
  const v2f cF2 = {cFs, cFs}, sF2 = {sFs, sFs};
  __syncthreads();

  float* yp = y + base * DI + dA;

#pragma unroll 4
  for (int tt = 0; tt < CLEN; ++tt) {
    const int ro = tt * 32;
    v2f xin = *(const v2f*)&lds[ro + 2 * ca];
    v2f dtd = *(const v2f*)&lds[1024 + ro + 2 * ca];
    v2f Br2, Bi2, Cr2, Ci2;               // lo-only; hi broadcast via op_sel_hi
    Br2.x = lds[2048 + ro + j];
    Bi2.x = lds[2048 + ro + j + 16];
    Cr2.x = lds[3072 + ro + j];
    Ci2.x = lds[3072 + ro + j + 16];
    v2f hr = pk_mul(dtd, Ar), hi2 = pk_mul(dtd, Ai);
    v2f invr = pk_fma(hr, pk_fma(hr, pk_add(hr, one), one), one);
    v2f invi = pk_fma(hi2, pk_fma(hi2, pk_add(hi2, one), one), one);
    v2f dx = pk_mul(dtd, xin);
    v2f gr = pk_fma_b(dx, Br2, pk_add(sr, sr));
    v2f gi = pk_fma_b(dx, Bi2, pk_add(si, si));
    v2f tr = pk_fms(invr, gr, sr);
    v2f ti = pk_fms(invi, gi, si);
    sr = pk_fms(tr, cs2, pk_mul(ti, sn2));
    si = pk_fma(tr, sn2, pk_mul(ti, cs2));
    v2f p = pk_fma_b(si, Ci2, pk_mul_b(sr, Cr2));
    float pA = row16_sum(p.x);
    float pB = row16_sum(p.y);
    if (j == 0) *(float2*)&yp[tt * DI] = make_float2(pA, pB);
    v2f ocs = cs2;
    cs2 = pk_fms(cs2, cF2, pk_mul(sn2, sF2));
    sn2 = pk_fma(sn2, cF2, pk_mul(ocs, sF2));
  }
  if (c == NCH - 1) {
    fstate[((size_t)b * DI + dA) * DS + j]          = sr.x;
    fstate[((size_t)b * DI + dA) * DS + j + 16]     = si.x;
    fstate[((size_t)b * DI + dA + 1) * DS + j]      = sr.y;
    fstate[((size_t)b * DI + dA + 1) * DS + j + 16] = si.y;
  }
}

// ---------------- gate (y * silu(z)) + LayerNorm, bf16 output ----------------
__global__ __launch_bounds__(256) void gate_ln(const float* __restrict__ y,
                                               const float* __restrict__ zb,
                                               const float* __restrict__ lw,
                                               const float* __restrict__ lb,
                                               unsigned short* __restrict__ o) {
  int tok = blockIdx.x;
  int t = threadIdx.x;
  float g[8];
  float sum = 0.f, sq = 0.f;
#pragma unroll
  for (int i = 0; i < 8; ++i) {
    int dd = t + i * 256;
    float yv = y[(size_t)tok * DI + dd];
    float zv = zb[(size_t)tok * DI + dd];
    float sg = zv / (1.f + __expf(-zv));
    float v = yv * sg;
    g[i] = v; sum += v; sq += v * v;
  }
#pragma unroll
  for (int off = 32; off; off >>= 1) { sum += __shfl_xor(sum, off); sq += __shfl_xor(sq, off); }
  __shared__ float rs[4], rq[4];
  int w = t >> 6;
  if ((t & 63) == 0) { rs[w] = sum; rq[w] = sq; }
  __syncthreads();
  sum = rs[0] + rs[1] + rs[2] + rs[3];
  sq  = rq[0] + rq[1] + rq[2] + rq[3];
  float mu = sum * (1.f / DI);
  float var = sq * (1.f / DI) - mu * mu;
  float rstd = rsqrtf(var + 1e-5f);
#pragma unroll
  for (int i = 0; i < 8; ++i) {
    int dd = t + i * 256;
    o[(size_t)tok * DI + dd] = f2bf((g[i] - mu) * rstd * lw[dd] + lb[dd]);
  }
}

// ---------------- launch ----------------
extern "C" void kernel_launch(void* const* d_in, const int* in_sizes, int n_in,
                              void* d_out, int out_size, void* d_ws, size_t ws_size,
                              hipStream_t stream) {
  const float* x       = (const float*)d_in[0];
  const float* W_in    = (const float*)d_in[1];
  const float* A_log   = (const float*)d_in[2];
  const float* W_B     = (const float*)d_in[3];
  const float* W_C     = (const float*)d_in[4];
  const float* W_dt    = (const float*)d_in[5];
  const float* b_dt    = (const float*)d_in[6];
  const float* dt_bias = (const float*)d_in[7];
  const float* rope    = (const float*)d_in[8];
  const float* ln_w    = (const float*)d_in[9];
  const float* ln_b    = (const float*)d_in[10];
  const float* W_out   = (const float*)d_in[11];
  float* out = (float*)d_out;
  float* ws = (float*)d_ws;

  // workspace layout (float offsets); overlays noted
  float* xs   = ws;                                   // [0, 2097152)
  float* zb   = ws + 2097152;                         // [2097152, 4194304)
  float* dts  = ws + 4194304;                         // [4194304, 6291456)
  float* bcb  = ws + 6291456;                         // [6291456, 6356992)
  unsigned short* wob  = (unsigned short*)(ws + 6356992);  // 2M bf16   [.., 7405568)
  unsigned short* xb   = (unsigned short*)(ws + 7405568);  // 1M bf16   [.., 7929856)
  unsigned short* wcat = (unsigned short*)(ws + 7929856);  // 6.42M bf16 [.., 11141120)
  float* yb   = ws + 11141120;                        // 2097152 f  [.., 13238272)
  unsigned short* lnb = (unsigned short*)(ws + 13238272);  // 2M bf16 [.., 14286848)
  float* Pbuf = ws + 14286848;                        // 15*6*32768*2 f = 5.9M [.., 20185088)
  float* Sbuf = ws + 20185088;                        // 16*32768*4 f = 2M [.., 22282240)
  float* fstate = out + (size_t)TOK * DM;

  // 1) fused bf16 casts (x, W_in, W_dt, W_B, W_C, W_out)
  fused_cast<<<4640, 256, 0, stream>>>(x, W_in, W_dt, W_B, W_C, W_out, xb, wcat, wob);
  // 2) fused input GEMM, 128x64 tiles, BK=64, swizzled LDS, 784 blocks, XCD-swizzled
  gemm1_big<<<784, 256, 0, stream>>>(xb, wcat, xs, zb, dts, bcb, b_dt, dt_bias);
  // 3) 3-phase chunked scan: p1 (chunk transfers) -> p2 (prefix compose) -> p3 (y-scan)
  scan_p1<<<(NCH - 1) * 128, 256, 0, stream>>>(xs, dts, bcb, A_log, rope, Pbuf);
  scan_p2<<<NPAIRH / 256, 256, 0, stream>>>(Pbuf, Sbuf);
  scan_p3<<<NCH * 128, 256, 0, stream>>>(xs, dts, bcb, A_log, rope, Sbuf, yb, fstate);
  // 4) gate + LN (bf16 out)
  gate_ln<<<TOK, 256, 0, stream>>>(yb, zb, ln_w, ln_b, lnb);
  // 5) out = ln @ W_out^T, in-block split-K (8 waves), writes out directly
  gemm2_fused<<<256, 512, 0, stream>>>(lnb, wob, out);
}

// Round 8
// 194.379 us; speedup vs baseline: 1.0438x; 1.0438x over previous
//
#include <hip/hip_runtime.h>
#include <math.h>

// Problem constants
#define B_SZ 2
#define SEQ 512
#define DM 1024
#define DI 2048
#define DS 32
#define TOK (B_SZ*SEQ)        // 1024
#define NCH 16                // scan chunks
#define CLEN (SEQ/NCH)        // 32
#define NPAIRH 32768          // (b, d-pair, j) chain-pair ids

// fused weight layout (rows of K=1024, bf16):
//   [0,4096) W_in | [4096,6144) W_dt | [6144,6176) W_B | [6176,6208) W_C | [6208,6272) pad
#define NFUSED 6272

typedef float v2f __attribute__((ext_vector_type(2)));

__device__ __forceinline__ unsigned short f2bf(float f) {
  unsigned int u = __builtin_bit_cast(unsigned int, f);
  unsigned int r = u + 0x7fffu + ((u >> 16) & 1u);   // RNE (inputs finite)
  return (unsigned short)(r >> 16);
}

// ---- packed-FP32 (VOP3P) helpers: 1 instruction per 2-wide op ----
static __device__ __forceinline__ v2f pk_fma(v2f a, v2f b, v2f c) {
  v2f d;
  asm("v_pk_fma_f32 %0, %1, %2, %3" : "=v"(d) : "v"(a), "v"(b), "v"(c));
  return d;
}
static __device__ __forceinline__ v2f pk_fms(v2f a, v2f b, v2f c) {
  v2f d;
  asm("v_pk_fma_f32 %0, %1, %2, %3 neg_lo:[0,0,1] neg_hi:[0,0,1]"
      : "=v"(d) : "v"(a), "v"(b), "v"(c));
  return d;
}
static __device__ __forceinline__ v2f pk_mul(v2f a, v2f b) {
  v2f d;
  asm("v_pk_mul_f32 %0, %1, %2" : "=v"(d) : "v"(a), "v"(b));
  return d;
}
static __device__ __forceinline__ v2f pk_add(v2f a, v2f b) {
  v2f d;
  asm("v_pk_add_f32 %0, %1, %2" : "=v"(d) : "v"(a), "v"(b));
  return d;
}
// d = a * bcast(b.lo) + c   (src1 hi half reads its LO 32 bits)
static __device__ __forceinline__ v2f pk_fma_b(v2f a, v2f b, v2f c) {
  v2f d;
  asm("v_pk_fma_f32 %0, %1, %2, %3 op_sel_hi:[1,0,1]"
      : "=v"(d) : "v"(a), "v"(b), "v"(c));
  return d;
}
// d = a * bcast(b.lo)
static __device__ __forceinline__ v2f pk_mul_b(v2f a, v2f b) {
  v2f d;
  asm("v_pk_mul_f32 %0, %1, %2 op_sel_hi:[1,0]"
      : "=v"(d) : "v"(a), "v"(b));
  return d;
}

// DPP row-rotate add: sums over the 16-lane row with 4 VALU ops (no LDS pipe).
template<int CTRL>
__device__ __forceinline__ float row_ror_add(float x) {
  int s = __builtin_amdgcn_update_dpp(0, __builtin_bit_cast(int, x), CTRL, 0xf, 0xf, false);
  return x + __builtin_bit_cast(float, s);
}
__device__ __forceinline__ float row16_sum(float v) {
  v = row_ror_add<0x121>(v);
  v = row_ror_add<0x122>(v);
  v = row_ror_add<0x124>(v);
  v = row_ror_add<0x128>(v);
  return v;
}

// ---------------- fused fp32 -> bf16 cast of all 6 tensors, 8 elems/thread ----------------
__global__ __launch_bounds__(256) void fused_cast(const float* __restrict__ x,
                                                  const float* __restrict__ W_in,
                                                  const float* __restrict__ W_dt,
                                                  const float* __restrict__ W_B,
                                                  const float* __restrict__ W_C,
                                                  const float* __restrict__ W_out,
                                                  unsigned short* __restrict__ xb,
                                                  unsigned short* __restrict__ wcat,
                                                  unsigned short* __restrict__ wob) {
  int g = blockIdx.x * 256 + threadIdx.x;
  const float* s; unsigned short* dd; int off;
  if      (g <  131072) { s = x;     dd = xb;             off = 0; }
  else if (g <  655360) { s = W_in;  dd = wcat;           off = 131072; }
  else if (g <  917504) { s = W_dt;  dd = wcat + 4194304; off = 655360; }
  else if (g <  921600) { s = W_B;   dd = wcat + 6291456; off = 917504; }
  else if (g <  925696) { s = W_C;   dd = wcat + 6324224; off = 921600; }
  else if (g < 1187840) { s = W_out; dd = wob;            off = 925696; }
  else return;
  int i = g - off;
  float4 a = ((const float4*)s)[i * 2];
  float4 b = ((const float4*)s)[i * 2 + 1];
  union { unsigned short us[8]; uint4 v; } o;
  o.us[0] = f2bf(a.x); o.us[1] = f2bf(a.y); o.us[2] = f2bf(a.z); o.us[3] = f2bf(a.w);
  o.us[4] = f2bf(b.x); o.us[5] = f2bf(b.y); o.us[6] = f2bf(b.z); o.us[7] = f2bf(b.w);
  ((uint4*)dd)[i] = o.v;
}

// ---------------- bf16 MFMA GEMM machinery ----------
typedef __attribute__((ext_vector_type(8))) short  frag8;
typedef __attribute__((ext_vector_type(4))) float  facc4;

__device__ __forceinline__ void gload_lds16(const unsigned short* g, unsigned short* l) {
  __builtin_amdgcn_global_load_lds((const __attribute__((address_space(1))) unsigned int*)g,
                                   (__attribute__((address_space(3))) unsigned int*)l, 16, 0, 0);
}
__device__ __forceinline__ void gload_lds16f(const float* g, float* l) {
  __builtin_amdgcn_global_load_lds((const __attribute__((address_space(1))) unsigned int*)g,
                                   (__attribute__((address_space(3))) unsigned int*)l, 16, 0, 0);
}

__device__ __forceinline__ float softplus_fast(float v) {
  return fmaxf(v, 0.f) + __logf(1.f + __expf(-fabsf(v)));
}

// ---------------- GEMM1: 128(M)x64(N) tile, BK=64, XOR-swizzled LDS, routed epilogue ------
__global__ __launch_bounds__(256) void gemm1_big(const unsigned short* __restrict__ A,
                                                 const unsigned short* __restrict__ Bw,
                                                 float* __restrict__ o_xs,
                                                 float* __restrict__ o_zb,
                                                 float* __restrict__ o_dts,
                                                 float* __restrict__ o_bcb,
                                                 const float* __restrict__ b_dt,
                                                 const float* __restrict__ dt_bias) {
  __shared__ __align__(16) unsigned short As[128 * 64];   // 16 KB
  __shared__ __align__(16) unsigned short Bs[64 * 64];    // 8 KB
  const int K = DM;
  const int tid = threadIdx.x;
  const int w = tid >> 6, lane = tid & 63;
  const int wm = w >> 1, wn = w & 1;
  const int bid = blockIdx.x;
  const int Wk = (bid & 7) * 98 + (bid >> 3);   // XCD-contiguous walk
  const int m0 = (Wk & 7) * 128;                // 8 m-tiles share one B n-column per XCD chunk
  const int n0 = (Wk >> 3) * 64;
  const int r = lane & 15, q = lane >> 4;
  const int srow = lane >> 3;                   // staging row-in-chunk (0..7)
  const int scol = ((lane & 7) ^ srow) * 8;     // XOR-swizzled source k-seg
  facc4 acc[4][2] = {};
  const unsigned short* Ag = A + (size_t)m0 * K;
  const unsigned short* Bg = Bw + (size_t)n0 * K;

  for (int k0 = 0; k0 < DM; k0 += 64) {
#pragma unroll
    for (int k = 0; k < 4; ++k) {               // A: 16 chunks of 8 rows x 64 k (1 KB)
      int ch = w * 4 + k;
      gload_lds16(Ag + (size_t)(ch * 8 + srow) * K + k0 + scol, &As[ch * 512]);
    }
#pragma unroll
    for (int k = 0; k < 2; ++k) {               // B: 8 chunks
      int ch = w * 2 + k;
      gload_lds16(Bg + (size_t)(ch * 8 + srow) * K + k0 + scol, &Bs[ch * 512]);
    }
    __syncthreads();                            // drains global_load_lds
#pragma unroll
    for (int kk = 0; kk < 2; ++kk) {
      frag8 af[4], bfr[2];
      const int sw = ((kk * 4 + q) ^ (r & 7)) * 8;    // swizzled seg offset (row&7 == r&7)
#pragma unroll
      for (int i = 0; i < 4; ++i)
        af[i] = *(const frag8*)&As[(wm * 64 + i * 16 + r) * 64 + sw];
#pragma unroll
      for (int jj = 0; jj < 2; ++jj)
        bfr[jj] = *(const frag8*)&Bs[(wn * 32 + jj * 16 + r) * 64 + sw];
#pragma unroll
      for (int i = 0; i < 4; ++i)
#pragma unroll
        for (int jj = 0; jj < 2; ++jj)
          acc[i][jj] = __builtin_amdgcn_mfma_f32_16x16x32_bf16(af[i], bfr[jj], acc[i][jj], 0, 0, 0);
    }
    __syncthreads();
  }

#pragma unroll
  for (int i = 0; i < 4; ++i) {
#pragma unroll
    for (int jj = 0; jj < 2; ++jj) {
      int n = n0 + wn * 32 + jj * 16 + r;
      int mb = m0 + wm * 64 + i * 16 + q * 4;
      if (n < 2048) {
#pragma unroll
        for (int rg = 0; rg < 4; ++rg)
          o_xs[(size_t)(mb + rg) * DI + n] = acc[i][jj][rg];
      } else if (n < 4096) {
#pragma unroll
        for (int rg = 0; rg < 4; ++rg)
          o_zb[(size_t)(mb + rg) * DI + (n - 2048)] = acc[i][jj][rg];
      } else if (n < 6144) {
        int d = n - 4096;
        float bias = b_dt[d] + dt_bias[d];
#pragma unroll
        for (int rg = 0; rg < 4; ++rg)
          o_dts[(size_t)(mb + rg) * DI + d] = softplus_fast(acc[i][jj][rg] + bias);
      } else if (n < 6176) {
#pragma unroll
        for (int rg = 0; rg < 4; ++rg)
          o_bcb[(size_t)(mb + rg) * DS + (n - 6144)] = acc[i][jj][rg];
      } else if (n < 6208) {
#pragma unroll
        for (int rg = 0; rg < 4; ++rg)
          o_bcb[(size_t)TOK * DS + (size_t)(mb + rg) * DS + (n - 6176)] = acc[i][jj][rg];
      }
    }
  }
}

// ---------------- GEMM2: out = ln @ W_out^T with IN-BLOCK split-K (8 waves) ----------------
__global__ __launch_bounds__(512) void gemm2_fused(const unsigned short* __restrict__ A,
                                                   const unsigned short* __restrict__ Bw,
                                                   float* __restrict__ o_c) {
  __shared__ __align__(16) unsigned short As[2][64 * 64];   // 16 KB
  __shared__ __align__(16) unsigned short Bs[2][64 * 64];   // 16 KB
  const int K = DI;
  const int tid = threadIdx.x;
  const int grp = tid >> 8;                     // 0 or 1 (split-K half)
  const int w = (tid >> 6) & 3;
  const int lane = tid & 63;
  const int wm = w >> 1, wn = w & 1;
  const int bid = blockIdx.x;
  const int Wk = (bid & 7) * 32 + (bid >> 3);   // 256 blocks, bijective XCD walk
  const int m0 = (Wk % 16) * 64;
  const int n0 = (Wk / 16) * 64;
  const int r = lane & 15, q = lane >> 4;
  const int srow = lane >> 3;
  const int scol = ((lane & 7) ^ srow) * 8;
  facc4 acc[2][2] = {};
  const unsigned short* Ag = A + (size_t)m0 * K + grp * 1024;
  const unsigned short* Bg = Bw + (size_t)n0 * K + grp * 1024;
  unsigned short* Asg = As[grp];
  unsigned short* Bsg = Bs[grp];

  for (int k0 = 0; k0 < 1024; k0 += 64) {
#pragma unroll
    for (int k = 0; k < 2; ++k) {
      int ch = w * 2 + k;                // 8 chunks of 8 rows x 64 k per group
      gload_lds16(Ag + (size_t)(ch * 8 + srow) * K + k0 + scol, &Asg[ch * 512]);
      gload_lds16(Bg + (size_t)(ch * 8 + srow) * K + k0 + scol, &Bsg[ch * 512]);
    }
    __syncthreads();
#pragma unroll
    for (int kk = 0; kk < 2; ++kk) {
      frag8 af[2], bf[2];
      const int sw = ((kk * 4 + q) ^ (r & 7)) * 8;
#pragma unroll
      for (int i = 0; i < 2; ++i)
        af[i] = *(const frag8*)&Asg[(wm * 32 + i * 16 + r) * 64 + sw];
#pragma unroll
      for (int jj = 0; jj < 2; ++jj)
        bf[jj] = *(const frag8*)&Bsg[(wn * 32 + jj * 16 + r) * 64 + sw];
#pragma unroll
      for (int i = 0; i < 2; ++i)
#pragma unroll
        for (int jj = 0; jj < 2; ++jj)
          acc[i][jj] = __builtin_amdgcn_mfma_f32_16x16x32_bf16(af[i], bf[jj], acc[i][jj], 0, 0, 0);
    }
    __syncthreads();
  }

  // cross-group reduce via LDS (reuse As[0]: 16 KB holds the 64x64 fp32 tile)
  float* red = (float*)&As[0][0];
  if (grp == 1) {
#pragma unroll
    for (int i = 0; i < 2; ++i)
#pragma unroll
      for (int jj = 0; jj < 2; ++jj) {
        int coln = wn * 32 + jj * 16 + r;
        int rowb = wm * 32 + i * 16 + q * 4;
#pragma unroll
        for (int rg = 0; rg < 4; ++rg)
          red[(rowb + rg) * 64 + coln] = acc[i][jj][rg];
      }
  }
  __syncthreads();
  if (grp == 0) {
#pragma unroll
    for (int i = 0; i < 2; ++i)
#pragma unroll
      for (int jj = 0; jj < 2; ++jj) {
        int coln = wn * 32 + jj * 16 + r;
        int rowb = wm * 32 + i * 16 + q * 4;
#pragma unroll
        for (int rg = 0; rg < 4; ++rg)
          o_c[(size_t)(m0 + rowb + rg) * DM + n0 + coln] =
              acc[i][jj][rg] + red[(rowb + rg) * 64 + coln];
      }
  }
}

// ---------------- chunked scan, packed-FP32, NCH=16 (CLEN=32) ----------------
// Per (d,j): h = dt*A/2 (|h|<=0.07); inv = 1/(1-h) ~= 1+h+h^2+h^3;
// A_bar = 2*inv-1; s' = inv*(2s + dt*x*B) - s; then rotate (r,i).
__global__ __launch_bounds__(256) void scan_p1(const float* __restrict__ xs,
                                               const float* __restrict__ dts,
                                               const float* __restrict__ bcb,
                                               const float* __restrict__ A_log,
                                               const float* __restrict__ rope,
                                               float* __restrict__ Pbuf) {
  __shared__ __align__(16) float lds[3072];     // 12 KB: xs | dts | B
  const int blk = blockIdx.x;           // 1920 = 15 chunks x 128 (chunk 15's P,u never consumed)
  const int c = blk >> 7;
  const int sub = blk & 127;
  const int b = sub >> 6;
  const int dbase = (sub & 63) << 5;
  const int tid = threadIdx.x;
  const int wv = tid >> 6, lane = tid & 63;
  const int j = tid & 15;
  const int ca = (tid >> 4) & 15;
  const int l0 = c * CLEN;
  const size_t base = (size_t)(b * SEQ + l0);

  {
    int row = wv * 8 + (lane >> 3);     // 0..31 token within chunk
    int col = (lane & 7) << 2;
    gload_lds16f(xs  + (base + row) * DI + dbase + col, &lds[wv * 256]);
    gload_lds16f(dts + (base + row) * DI + dbase + col, &lds[1024 + wv * 256]);
    gload_lds16f(bcb + base * DS + wv * 256 + lane * 4, &lds[2048 + wv * 256]);
  }

  const int dA = dbase + 2 * ca;
  v2f Ar, Ai;
  Ar.x = -0.5f * __expf(A_log[dA * DS + j]);
  Ar.y = -0.5f * __expf(A_log[(dA + 1) * DS + j]);
  Ai.x = -0.5f * __expf(A_log[dA * DS + j + 16]);
  Ai.y = -0.5f * __expf(A_log[(dA + 1) * DS + j + 16]);
  const float fr = rope[j];
  float sn0, cs0, sFs, cFs;
  __sincosf((float)l0 * fr, &sn0, &cs0);
  __sincosf(fr, &sFs, &cFs);
  const v2f one = {1.f, 1.f};
  const v2f two = {2.f, 2.f};
  v2f cs2 = {cs0, cs0}, sn2 = {sn0, sn0};
  const v2f cF2 = {cFs, cFs}, sF2 = {sFs, sFs};
  __syncthreads();

  v2f p00 = one, p01 = {0.f, 0.f}, p10 = {0.f, 0.f}, p11 = one;
  v2f ur = {0.f, 0.f}, ui = {0.f, 0.f};

#pragma unroll 4
  for (int tt = 0; tt < CLEN; ++tt) {
    const int ro = tt * 32;
    v2f xin = *(const v2f*)&lds[ro + 2 * ca];
    v2f dtd = *(const v2f*)&lds[1024 + ro + 2 * ca];
    v2f Br2, Bi2;                         // lo-only; hi broadcast via op_sel_hi
    Br2.x = lds[2048 + ro + j];
    Bi2.x = lds[2048 + ro + j + 16];
    v2f hr = pk_mul(dtd, Ar), hi2 = pk_mul(dtd, Ai);
    v2f invr = pk_fma(hr, pk_fma(hr, pk_add(hr, one), one), one);
    v2f invi = pk_fma(hi2, pk_fma(hi2, pk_add(hi2, one), one), one);
    v2f dx = pk_mul(dtd, xin);
    v2f gr = pk_fma_b(dx, Br2, pk_add(ur, ur));
    v2f gi = pk_fma_b(dx, Bi2, pk_add(ui, ui));
    v2f tr = pk_fms(invr, gr, ur);
    v2f ti = pk_fms(invi, gi, ui);
    ur = pk_fms(tr, cs2, pk_mul(ti, sn2));
    ui = pk_fma(tr, sn2, pk_mul(ti, cs2));
    v2f Abr = pk_fms(invr, two, one);
    v2f Abi = pk_fms(invi, two, one);
    v2f q00 = pk_mul(Abr, p00), q01 = pk_mul(Abr, p01);
    v2f q10 = pk_mul(Abi, p10), q11 = pk_mul(Abi, p11);
    p00 = pk_fms(q00, cs2, pk_mul(q10, sn2));
    p10 = pk_fma(q00, sn2, pk_mul(q10, cs2));
    p01 = pk_fms(q01, cs2, pk_mul(q11, sn2));
    p11 = pk_fma(q01, sn2, pk_mul(q11, cs2));
    v2f ocs = cs2;
    cs2 = pk_fms(cs2, cF2, pk_mul(sn2, sF2));
    sn2 = pk_fma(sn2, cF2, pk_mul(ocs, sF2));
  }
  const int pc = (b * 1024 + (dbase >> 1) + ca) * 16 + j;
  float2* Pb2 = (float2*)Pbuf;
  Pb2[(c * 6 + 0) * NPAIRH + pc] = make_float2(p00.x, p00.y);
  Pb2[(c * 6 + 1) * NPAIRH + pc] = make_float2(p01.x, p01.y);
  Pb2[(c * 6 + 2) * NPAIRH + pc] = make_float2(p10.x, p10.y);
  Pb2[(c * 6 + 3) * NPAIRH + pc] = make_float2(p11.x, p11.y);
  Pb2[(c * 6 + 4) * NPAIRH + pc] = make_float2(ur.x, ur.y);
  Pb2[(c * 6 + 5) * NPAIRH + pc] = make_float2(ui.x, ui.y);
}

__global__ __launch_bounds__(256) void scan_p3(const float* __restrict__ xs,
                                               const float* __restrict__ dts,
                                               const float* __restrict__ bcb,
                                               const float* __restrict__ A_log,
                                               const float* __restrict__ rope,
                                               const float* __restrict__ Pbuf,
                                               float* __restrict__ y,
                                               float* __restrict__ fstate) {
  __shared__ __align__(16) float lds[4096];     // 16 KB: xs | dts | B | C
  const int blk = blockIdx.x;           // 2048
  const int c = blk >> 7;
  const int sub = blk & 127;
  const int b = sub >> 6;
  const int dbase = (sub & 63) << 5;
  const int tid = threadIdx.x;
  const int wv = tid >> 6, lane = tid & 63;
  const int j = tid & 15;
  const int ca = (tid >> 4) & 15;
  const int l0 = c * CLEN;
  const size_t base = (size_t)(b * SEQ + l0);

  {
    int row = wv * 8 + (lane >> 3);
    int col = (lane & 7) << 2;
    gload_lds16f(xs  + (base + row) * DI + dbase + col, &lds[wv * 256]);
    gload_lds16f(dts + (base + row) * DI + dbase + col, &lds[1024 + wv * 256]);
    gload_lds16f(bcb + base * DS + wv * 256 + lane * 4, &lds[2048 + wv * 256]);
    gload_lds16f(bcb + (size_t)TOK * DS + base * DS + wv * 256 + lane * 4,
                 &lds[3072 + wv * 256]);
  }

  const int dA = dbase + 2 * ca;
  v2f Ar, Ai;
  Ar.x = -0.5f * __expf(A_log[dA * DS + j]);
  Ar.y = -0.5f * __expf(A_log[(dA + 1) * DS + j]);
  Ai.x = -0.5f * __expf(A_log[dA * DS + j + 16]);
  Ai.y = -0.5f * __expf(A_log[(dA + 1) * DS + j + 16]);
  const float fr = rope[j];
  float sn0, cs0, sFs, cFs;
  __sincosf((float)l0 * fr, &sn0, &cs0);
  __sincosf(fr, &sFs, &cFs);
  const v2f one = {1.f, 1.f};
  v2f cs2 = {cs0, cs0}, sn2 = {sn0, sn0};
  const v2f cF2 = {cFs, cFs}, sF2 = {sFs, sFs};

  // compose entry state from prior chunks (overlaps the staging drain)
  const int pc = (b * 1024 + (dbase >> 1) + ca) * 16 + j;
  const float2* Pb2 = (const float2*)Pbuf;
  v2f sr = {0.f, 0.f}, si = {0.f, 0.f};
  for (int k = 0; k < c; ++k) {
    float2 f;
    f = Pb2[(k * 6 + 0) * NPAIRH + pc]; v2f p00 = {f.x, f.y};
    f = Pb2[(k * 6 + 1) * NPAIRH + pc]; v2f p01 = {f.x, f.y};
    f = Pb2[(k * 6 + 2) * NPAIRH + pc]; v2f p10 = {f.x, f.y};
    f = Pb2[(k * 6 + 3) * NPAIRH + pc]; v2f p11 = {f.x, f.y};
    f = Pb2[(k * 6 + 4) * NPAIRH + pc]; v2f ur  = {f.x, f.y};
    f = Pb2[(k * 6 + 5) * NPAIRH + pc]; v2f ui  = {f.x, f.y};
    v2f nr = p00 * sr + p01 * si + ur;
    v2f ni = p10 * sr + p11 * si + ui;
    sr = nr; si = ni;
  }
  __syncthreads();

  float* yp = y + base * DI + dA;

#pragma unroll 4
  for (int tt = 0; tt < CLEN; ++tt) {
    const int ro = tt * 32;
    v2f xin = *(const v2f*)&lds[ro + 2 * ca];
    v2f dtd = *(const v2f*)&lds[1024 + ro + 2 * ca];
    v2f Br2, Bi2, Cr2, Ci2;               // lo-only; hi broadcast via op_sel_hi
    Br2.x = lds[2048 + ro + j];
    Bi2.x = lds[2048 + ro + j + 16];
    Cr2.x = lds[3072 + ro + j];
    Ci2.x = lds[3072 + ro + j + 16];
    v2f hr = pk_mul(dtd, Ar), hi2 = pk_mul(dtd, Ai);
    v2f invr = pk_fma(hr, pk_fma(hr, pk_add(hr, one), one), one);
    v2f invi = pk_fma(hi2, pk_fma(hi2, pk_add(hi2, one), one), one);
    v2f dx = pk_mul(dtd, xin);
    v2f gr = pk_fma_b(dx, Br2, pk_add(sr, sr));
    v2f gi = pk_fma_b(dx, Bi2, pk_add(si, si));
    v2f tr = pk_fms(invr, gr, sr);
    v2f ti = pk_fms(invi, gi, si);
    sr = pk_fms(tr, cs2, pk_mul(ti, sn2));
    si = pk_fma(tr, sn2, pk_mul(ti, cs2));
    v2f p = pk_fma_b(si, Ci2, pk_mul_b(sr, Cr2));
    float pA = row16_sum(p.x);
    float pB = row16_sum(p.y);
    if (j == 0) *(float2*)&yp[tt * DI] = make_float2(pA, pB);
    v2f ocs = cs2;
    cs2 = pk_fms(cs2, cF2, pk_mul(sn2, sF2));
    sn2 = pk_fma(sn2, cF2, pk_mul(ocs, sF2));
  }
  if (c == NCH - 1) {
    fstate[((size_t)b * DI + dA) * DS + j]          = sr.x;
    fstate[((size_t)b * DI + dA) * DS + j + 16]     = si.x;
    fstate[((size_t)b * DI + dA + 1) * DS + j]      = sr.y;
    fstate[((size_t)b * DI + dA + 1) * DS + j + 16] = si.y;
  }
}

// ---------------- gate (y * silu(z)) + LayerNorm, bf16 output ----------------
__global__ __launch_bounds__(256) void gate_ln(const float* __restrict__ y,
                                               const float* __restrict__ zb,
                                               const float* __restrict__ lw,
                                               const float* __restrict__ lb,
                                               unsigned short* __restrict__ o) {
  int tok = blockIdx.x;
  int t = threadIdx.x;
  float g[8];
  float sum = 0.f, sq = 0.f;
#pragma unroll
  for (int i = 0; i < 8; ++i) {
    int dd = t + i * 256;
    float yv = y[(size_t)tok * DI + dd];
    float zv = zb[(size_t)tok * DI + dd];
    float sg = zv / (1.f + __expf(-zv));
    float v = yv * sg;
    g[i] = v; sum += v; sq += v * v;
  }
#pragma unroll
  for (int off = 32; off; off >>= 1) { sum += __shfl_xor(sum, off); sq += __shfl_xor(sq, off); }
  __shared__ float rs[4], rq[4];
  int w = t >> 6;
  if ((t & 63) == 0) { rs[w] = sum; rq[w] = sq; }
  __syncthreads();
  sum = rs[0] + rs[1] + rs[2] + rs[3];
  sq  = rq[0] + rq[1] + rq[2] + rq[3];
  float mu = sum * (1.f / DI);
  float var = sq * (1.f / DI) - mu * mu;
  float rstd = rsqrtf(var + 1e-5f);
#pragma unroll
  for (int i = 0; i < 8; ++i) {
    int dd = t + i * 256;
    o[(size_t)tok * DI + dd] = f2bf((g[i] - mu) * rstd * lw[dd] + lb[dd]);
  }
}

// ---------------- launch ----------------
extern "C" void kernel_launch(void* const* d_in, const int* in_sizes, int n_in,
                              void* d_out, int out_size, void* d_ws, size_t ws_size,
                              hipStream_t stream) {
  const float* x       = (const float*)d_in[0];
  const float* W_in    = (const float*)d_in[1];
  const float* A_log   = (const float*)d_in[2];
  const float* W_B     = (const float*)d_in[3];
  const float* W_C     = (const float*)d_in[4];
  const float* W_dt    = (const float*)d_in[5];
  const float* b_dt    = (const float*)d_in[6];
  const float* dt_bias = (const float*)d_in[7];
  const float* rope    = (const float*)d_in[8];
  const float* ln_w    = (const float*)d_in[9];
  const float* ln_b    = (const float*)d_in[10];
  const float* W_out   = (const float*)d_in[11];
  float* out = (float*)d_out;
  float* ws = (float*)d_ws;

  // workspace layout (float offsets); overlays noted
  float* xs   = ws;                                   // [0, 2097152)
  float* zb   = ws + 2097152;                         // [2097152, 4194304)
  float* dts  = ws + 4194304;                         // [4194304, 6291456)
  float* bcb  = ws + 6291456;                         // [6291456, 6356992)
  unsigned short* wob  = (unsigned short*)(ws + 6356992);  // 2M bf16   [.., 7405568)
  unsigned short* xb   = (unsigned short*)(ws + 7405568);  // 1M bf16   [.., 7929856)
  unsigned short* wcat = (unsigned short*)(ws + 7929856);  // 6.42M bf16 [.., 11141120)
  float* yb   = ws + 11141120;                        // 2097152 f  [.., 13238272)
  unsigned short* lnb = (unsigned short*)(ws + 13238272);  // 2M bf16 [.., 14286848)
  float* Pbuf = ws + 14286848;                        // 15*6*32768*2 f = 5.9M [.., 20185088)
  float* fstate = out + (size_t)TOK * DM;

  // 1) fused bf16 casts (x, W_in, W_dt, W_B, W_C, W_out)
  fused_cast<<<4640, 256, 0, stream>>>(x, W_in, W_dt, W_B, W_C, W_out, xb, wcat, wob);
  // 2) fused input GEMM, 128x64 tiles, BK=64, swizzled LDS, 784 blocks, XCD-swizzled
  gemm1_big<<<784, 256, 0, stream>>>(xb, wcat, xs, zb, dts, bcb, b_dt, dt_bias);
  // 3) chunked scan, NCH=16: p1 (local P,u; chunk 15 skipped) then p3 (compose + re-scan)
  scan_p1<<<(NCH - 1) * 128, 256, 0, stream>>>(xs, dts, bcb, A_log, rope, Pbuf);
  scan_p3<<<NCH * 128, 256, 0, stream>>>(xs, dts, bcb, A_log, rope, Pbuf, yb, fstate);
  // 4) gate + LN (bf16 out)
  gate_ln<<<TOK, 256, 0, stream>>>(yb, zb, ln_w, ln_b, lnb);
  // 5) out = ln @ W_out^T, in-block split-K (8 waves), writes out directly
  gemm2_fused<<<256, 512, 0, stream>>>(lnb, wob, out);
}